// Round 1
// baseline (6957.201 us; speedup 1.0000x reference)
//
#include <hip/hip_runtime.h>
#include <hip/hip_bf16.h>
#include <math.h>

#define D_MODEL 2048
#define EDIM    4096
#define NSTATE  16
#define LSEQ    256
#define BATCH   4
#define NLAYER  6
#define FDIM    80

__device__ __forceinline__ float silu_f(float x) { return x / (1.f + __expf(-x)); }

// ---------------- embedding: h[b,l,:] = x[b,:,l]^T @ W_emb + b_emb ----------------
__global__ __launch_bounds__(256) void embed_kernel(
    const float* __restrict__ x, const float* __restrict__ W,
    const float* __restrict__ bias, float* __restrict__ h)
{
  int col = blockIdx.x * 256 + threadIdx.x;   // 0..2047
  int row = blockIdx.y;                        // 0..1023  (b*256 + l)
  int b = row >> 8, l = row & 255;
  const float* xp = x + (size_t)b * FDIM * LSEQ + l;
  float acc = bias[col];
  #pragma unroll 8
  for (int f = 0; f < FDIM; ++f)
    acc = fmaf(xp[(size_t)f * LSEQ], W[(size_t)f * D_MODEL + col], acc);
  h[(size_t)row * D_MODEL + col] = acc;
}

// ---------------- rmsnorm: u = h * rsqrt(mean(h^2)+eps) * w ----------------
__global__ __launch_bounds__(256) void rmsnorm_kernel(
    const float* __restrict__ h, const float* __restrict__ w, float* __restrict__ u)
{
  int row = blockIdx.x;
  const float* hr = h + (size_t)row * D_MODEL;
  float s = 0.f;
  for (int i = threadIdx.x; i < D_MODEL; i += 256) { float v = hr[i]; s = fmaf(v, v, s); }
  #pragma unroll
  for (int o = 32; o > 0; o >>= 1) s += __shfl_down(s, o);
  __shared__ float red[4];
  int lane = threadIdx.x & 63, wid = threadIdx.x >> 6;
  if (lane == 0) red[wid] = s;
  __syncthreads();
  float total = red[0] + red[1] + red[2] + red[3];
  float scale = rsqrtf(total * (1.f / D_MODEL) + 1e-5f);
  float* ur = u + (size_t)row * D_MODEL;
  for (int i = threadIdx.x; i < D_MODEL; i += 256) ur[i] = hr[i] * scale * w[i];
}

// ---------------- generic fp32 tiled GEMM: C = A@B + bias (+ resid) ----------------
// grid = (N/128, M/64), block = 256. Each thread: 4x8 micro-tile.
__global__ __launch_bounds__(256) void gemm_f32(
    const float* __restrict__ A, int lda,
    const float* __restrict__ B, int ldb,
    const float* __restrict__ bias,
    const float* resid, int ldr,
    float* C, int ldc, int K)
{
  __shared__ float As[16][68];   // [k][m], +4 pad: conflict-free, 16B-aligned rows
  __shared__ float Bs[16][128];
  const int tid = threadIdx.x;
  const int bm = blockIdx.y * 64;
  const int bn = blockIdx.x * 128;
  const int ty = tid >> 4;          // 0..15
  const int tx = tid & 15;          // 0..15
  const int a_row = tid >> 2;       // 0..63
  const int a_col = (tid & 3) << 2; // 0,4,8,12
  const int b_row = tid >> 5;       // 0..7
  const int b_col = (tid & 31) << 2;
  float acc[4][8] = {};
  for (int k0 = 0; k0 < K; k0 += 16) {
    float4 av = *(const float4*)(A + (size_t)(bm + a_row) * lda + k0 + a_col);
    As[a_col + 0][a_row] = av.x;
    As[a_col + 1][a_row] = av.y;
    As[a_col + 2][a_row] = av.z;
    As[a_col + 3][a_row] = av.w;
    float4 bv0 = *(const float4*)(B + (size_t)(k0 + b_row) * ldb + bn + b_col);
    float4 bv1 = *(const float4*)(B + (size_t)(k0 + b_row + 8) * ldb + bn + b_col);
    *(float4*)&Bs[b_row][b_col] = bv0;
    *(float4*)&Bs[b_row + 8][b_col] = bv1;
    __syncthreads();
    #pragma unroll
    for (int k = 0; k < 16; ++k) {
      float a[4], bb[8];
      *(float4*)a       = *(const float4*)&As[k][ty << 2];
      *(float4*)&bb[0]  = *(const float4*)&Bs[k][tx << 3];
      *(float4*)&bb[4]  = *(const float4*)&Bs[k][(tx << 3) + 4];
      #pragma unroll
      for (int i = 0; i < 4; ++i)
        #pragma unroll
        for (int j = 0; j < 8; ++j)
          acc[i][j] = fmaf(a[i], bb[j], acc[i][j]);
    }
    __syncthreads();
  }
  #pragma unroll
  for (int i = 0; i < 4; ++i) {
    const int row = bm + (ty << 2) + i;
    const int col = bn + (tx << 3);
    float o[8];
    #pragma unroll
    for (int j = 0; j < 8; ++j) {
      float v = acc[i][j] + bias[col + j];
      if (resid) v += resid[(size_t)row * ldr + col + j];
      o[j] = v;
    }
    *(float4*)(C + (size_t)row * ldc + col)     = make_float4(o[0], o[1], o[2], o[3]);
    *(float4*)(C + (size_t)row * ldc + col + 4) = make_float4(o[4], o[5], o[6], o[7]);
  }
}

// ---------------- depthwise causal conv (K=4) + silu: xz[:, :4096] -> xa ----------------
__global__ __launch_bounds__(256) void conv_silu_kernel(
    const float* __restrict__ xz, const float* __restrict__ cw,
    const float* __restrict__ cb, float* __restrict__ xa)
{
  int idx = blockIdx.x * 256 + threadIdx.x;  // over 1024*4096
  int e = idx & (EDIM - 1);
  int row = idx >> 12;                        // b*256 + l
  int l = row & (LSEQ - 1);
  float4 w = *(const float4*)(cw + (size_t)e * 4);
  const float* base = xz + (size_t)row * 8192 + e;
  float acc = cb[e];
  acc = fmaf(w.w, base[0], acc);
  if (l >= 1) acc = fmaf(w.z, base[-8192], acc);
  if (l >= 2) acc = fmaf(w.y, base[-2 * 8192], acc);
  if (l >= 3) acc = fmaf(w.x, base[-3 * 8192], acc);
  xa[idx] = silu_f(acc);
}

// ---------------- dbc = xa @ W_x  (1024 x 4096 x 34) ----------------
__global__ __launch_bounds__(256) void dbc_kernel(
    const float* __restrict__ xa, const float* __restrict__ Wx, float* __restrict__ dbc)
{
  int row = blockIdx.x;
  const float* ar = xa + (size_t)row * EDIM;
  float acc[34];
  #pragma unroll
  for (int j = 0; j < 34; ++j) acc[j] = 0.f;
  for (int k = threadIdx.x; k < EDIM; k += 256) {
    float av = ar[k];
    const float* wr = Wx + (size_t)k * 34;
    #pragma unroll
    for (int j = 0; j < 34; ++j) acc[j] = fmaf(av, wr[j], acc[j]);
  }
  __shared__ float red[34][4];
  int lane = threadIdx.x & 63, wid = threadIdx.x >> 6;
  #pragma unroll
  for (int j = 0; j < 34; ++j) {
    float v = acc[j];
    #pragma unroll
    for (int o = 32; o > 0; o >>= 1) v += __shfl_down(v, o);
    if (lane == 0) red[j][wid] = v;
  }
  __syncthreads();
  if (threadIdx.x < 34)
    dbc[(size_t)row * 34 + threadIdx.x] =
        red[threadIdx.x][0] + red[threadIdx.x][1] + red[threadIdx.x][2] + red[threadIdx.x][3];
}

// ---------------- dt = softplus(dbc[:, :2] @ W_dt + b_dt) ----------------
__global__ __launch_bounds__(256) void dtk_kernel(
    const float* __restrict__ dbc, const float* __restrict__ Wdt,
    const float* __restrict__ bdt, float* __restrict__ dtb)
{
  int idx = blockIdx.x * 256 + threadIdx.x;  // over 1024*4096
  int e = idx & (EDIM - 1);
  int row = idx >> 12;
  float d0 = dbc[(size_t)row * 34 + 0], d1 = dbc[(size_t)row * 34 + 1];
  float v = fmaf(d1, Wdt[EDIM + e], fmaf(d0, Wdt[e], bdt[e]));
  dtb[idx] = (v > 20.f) ? v : log1pf(expf(v));
}

// ---------------- selective scan, fused with y = (ys + Dp*xa) * silu(z) ----------------
// grid = 256 blocks (4 b x 64 e-chunks), block = 64 threads, one thread per channel e.
// y is written into the dead xp half of xz (stride 8192).
__global__ __launch_bounds__(64) void scan_kernel(
    const float* xz, const float* __restrict__ xa,
    const float* __restrict__ dtb, const float* __restrict__ dbc,
    const float* __restrict__ Alog, const float* __restrict__ Dpp,
    float* yout)
{
  int bx = blockIdx.x;
  int b = bx >> 6;
  int e = ((bx & 63) << 6) + threadIdx.x;
  float Aa[16], hh[16];
  #pragma unroll
  for (int n = 0; n < 16; ++n) { Aa[n] = -expf(Alog[(size_t)e * 16 + n]); hh[n] = 0.f; }
  float dpe = Dpp[e];
  for (int t = 0; t < LSEQ; ++t) {
    int row = (b << 8) + t;
    float dta = dtb[(size_t)row * EDIM + e];
    float xav = xa[(size_t)row * EDIM + e];
    float zv  = xz[(size_t)row * 8192 + EDIM + e];
    const float* dr = dbc + (size_t)row * 34;
    float dtxa = dta * xav;
    float ysum = 0.f;
    #pragma unroll
    for (int n = 0; n < 16; ++n) {
      float da = __expf(dta * Aa[n]);
      hh[n] = fmaf(da, hh[n], dtxa * dr[2 + n]);
      ysum = fmaf(hh[n], dr[18 + n], ysum);
    }
    float yv = fmaf(dpe, xav, ysum);
    yout[(size_t)row * 8192 + e] = yv * silu_f(zv);
  }
}

// ---------------- small head GEMMs: out[b,j] = act(bias[j] + in[b,:] @ W[:,j]) ----------------
__global__ __launch_bounds__(256) void head_gemm_kernel(
    const float* __restrict__ in, int row_stride,
    const float* __restrict__ W, const float* __restrict__ bias,
    float* __restrict__ outp, int K, int N, int act)
{
  __shared__ float sIn[2048];
  const float* inr = in + (size_t)blockIdx.y * row_stride;
  for (int k = threadIdx.x; k < K; k += 256) sIn[k] = inr[k];
  __syncthreads();
  int j = blockIdx.x * 256 + threadIdx.x;
  float acc = bias[j];
  #pragma unroll 4
  for (int k = 0; k < K; ++k)
    acc = fmaf(sIn[k], W[(size_t)k * N + j], acc);
  if (act == 1) acc = silu_f(acc);
  else if (act == 2) acc = (acc > 0.f) ? acc : 0.01f * acc;
  outp[(size_t)blockIdx.y * N + j] = acc;
}

__global__ __launch_bounds__(256) void head_final_kernel(
    const float* __restrict__ g2, const float* __restrict__ W,
    const float* __restrict__ bb, float* __restrict__ out)
{
  int b_idx = threadIdx.x >> 6;   // 0..3
  int lane = threadIdx.x & 63;
  float s = 0.f;
  #pragma unroll
  for (int i = 0; i < 4; ++i) {
    int k = lane + i * 64;
    s = fmaf(g2[b_idx * 256 + k], W[k], s);
  }
  #pragma unroll
  for (int o = 32; o > 0; o >>= 1) s += __shfl_down(s, o);
  if (lane == 0) out[b_idx] = 1.f / (1.f + __expf(-(s + bb[0])));
}

extern "C" void kernel_launch(void* const* d_in, const int* in_sizes, int n_in,
                              void* d_out, int out_size, void* d_ws, size_t ws_size,
                              hipStream_t stream)
{
  const float* x      = (const float*)d_in[0];
  const float* W_emb  = (const float*)d_in[1];
  const float* b_emb  = (const float*)d_in[2];
  const float* norm_w = (const float*)d_in[3];
  const float* W_in   = (const float*)d_in[4];
  const float* b_in   = (const float*)d_in[5];
  const float* conv_w = (const float*)d_in[6];
  const float* conv_b = (const float*)d_in[7];
  const float* W_x    = (const float*)d_in[8];
  const float* W_dt   = (const float*)d_in[9];
  const float* b_dt   = (const float*)d_in[10];
  const float* A_log  = (const float*)d_in[11];
  const float* Dp     = (const float*)d_in[12];
  const float* W_out  = (const float*)d_in[13];
  const float* b_out  = (const float*)d_in[14];
  const float* W_f    = (const float*)d_in[15];
  const float* b_f    = (const float*)d_in[16];
  const float* W_h1   = (const float*)d_in[17];
  const float* b_h1   = (const float*)d_in[18];
  const float* W_h2   = (const float*)d_in[19];
  const float* b_h2   = (const float*)d_in[20];
  const float* W_h3   = (const float*)d_in[21];
  const float* b_h3   = (const float*)d_in[22];
  float* out = (float*)d_out;

  // workspace layout (floats); total ~84 MB
  float* ws  = (float*)d_ws;
  float* h   = ws;                               // 1024*2048
  float* u   = h   + (size_t)1024 * 2048;        // 1024*2048
  float* xz  = u   + (size_t)1024 * 2048;        // 1024*8192 (xp half reused for y)
  float* xa  = xz  + (size_t)1024 * 8192;        // 1024*4096
  float* dtb = xa  + (size_t)1024 * 4096;        // 1024*4096
  float* dbc = dtb + (size_t)1024 * 4096;        // 1024*34
  float* fb  = dbc + (size_t)1024 * 34;          // 4*1024
  float* g1b = fb  + 4096;                       // 4*512
  float* g2b = g1b + 2048;                       // 4*256

  embed_kernel<<<dim3(D_MODEL / 256, 1024), 256, 0, stream>>>(x, W_emb, b_emb, h);

  for (int i = 0; i < NLAYER; ++i) {
    const float* Wi  = W_in  + (size_t)i * 2048 * 8192;
    const float* bi  = b_in  + (size_t)i * 8192;
    const float* cwi = conv_w + (size_t)i * 4096 * 4;
    const float* cbi = conv_b + (size_t)i * 4096;
    const float* Wxi = W_x   + (size_t)i * 4096 * 34;
    const float* Wdti= W_dt  + (size_t)i * 2 * 4096;
    const float* bdti= b_dt  + (size_t)i * 4096;
    const float* Ali = A_log + (size_t)i * 4096 * 16;
    const float* Dpi = Dp    + (size_t)i * 4096;
    const float* Woi = W_out + (size_t)i * 4096 * 2048;
    const float* boi = b_out + (size_t)i * 2048;
    const float* nwi = norm_w + (size_t)i * 2048;

    rmsnorm_kernel<<<1024, 256, 0, stream>>>(h, nwi, u);
    // xz = u @ W_in + b_in   (1024 x 2048 x 8192)
    gemm_f32<<<dim3(8192 / 128, 1024 / 64), 256, 0, stream>>>(
        u, 2048, Wi, 8192, bi, nullptr, 0, xz, 8192, 2048);
    conv_silu_kernel<<<(1024 * 4096) / 256, 256, 0, stream>>>(xz, cwi, cbi, xa);
    dbc_kernel<<<1024, 256, 0, stream>>>(xa, Wxi, dbc);
    dtk_kernel<<<(1024 * 4096) / 256, 256, 0, stream>>>(dbc, Wdti, bdti, dtb);
    // scan: y -> xp half of xz
    scan_kernel<<<256, 64, 0, stream>>>(xz, xa, dtb, dbc, Ali, Dpi, xz);
    // h = h + y @ W_out + b_out   (1024 x 4096 x 2048), y read from xz with lda=8192
    gemm_f32<<<dim3(2048 / 128, 1024 / 64), 256, 0, stream>>>(
        xz, 8192, Woi, 2048, boi, h, 2048, h, 2048, 4096);
  }

  // head: f = h[:, -1] @ W_f + b_f
  head_gemm_kernel<<<dim3(1024 / 256, BATCH), 256, 0, stream>>>(
      h + (size_t)255 * 2048, 256 * 2048, W_f, b_f, fb, 2048, 1024, 0);
  head_gemm_kernel<<<dim3(512 / 256, BATCH), 256, 0, stream>>>(
      fb, 1024, W_h1, b_h1, g1b, 1024, 512, 1);
  head_gemm_kernel<<<dim3(256 / 256, BATCH), 256, 0, stream>>>(
      g1b, 512, W_h2, b_h2, g2b, 512, 256, 2);
  head_final_kernel<<<1, 256, 0, stream>>>(g2b, W_h3, b_h3, out);
}

// Round 2
// 3238.114 us; speedup vs baseline: 2.1485x; 2.1485x over previous
//
#include <hip/hip_runtime.h>
#include <hip/hip_bf16.h>
#include <math.h>

#define D_MODEL 2048
#define EDIM    4096
#define NSTATE  16
#define LSEQ    256
#define BATCH   4
#define NLAYER  6
#define FDIM    80

typedef __attribute__((ext_vector_type(8))) short bf16x8;
typedef __attribute__((ext_vector_type(4))) float f32x4;

__device__ __forceinline__ float silu_f(float x) { return x / (1.f + __expf(-x)); }

// RNE float -> bf16 bits
__device__ __forceinline__ unsigned short f2bf(float f) {
  unsigned u = __float_as_uint(f);
  unsigned r = u + 0x7fffu + ((u >> 16) & 1u);
  return (unsigned short)(r >> 16);
}

__device__ __forceinline__ void gload_lds16(const void* g, void* l) {
  __builtin_amdgcn_global_load_lds(
      (const __attribute__((address_space(1))) unsigned int*)g,
      (__attribute__((address_space(3))) unsigned int*)l, 16, 0, 0);
}

// ---------------- embedding: h[b,l,:] = x[b,:,l]^T @ W_emb + b_emb ----------------
__global__ __launch_bounds__(256) void embed_kernel(
    const float* __restrict__ x, const float* __restrict__ W,
    const float* __restrict__ bias, float* __restrict__ h)
{
  int col = blockIdx.x * 256 + threadIdx.x;   // 0..2047
  int row = blockIdx.y;                        // 0..1023  (b*256 + l)
  int b = row >> 8, l = row & 255;
  const float* xp = x + (size_t)b * FDIM * LSEQ + l;
  float acc = bias[col];
  #pragma unroll 8
  for (int f = 0; f < FDIM; ++f)
    acc = fmaf(xp[(size_t)f * LSEQ], W[(size_t)f * D_MODEL + col], acc);
  h[(size_t)row * D_MODEL + col] = acc;
}

// ---------------- rmsnorm: u_bf16 = h * rsqrt(mean(h^2)+eps) * w ----------------
__global__ __launch_bounds__(256) void rmsnorm_kernel(
    const float* __restrict__ h, const float* __restrict__ w, unsigned short* __restrict__ u)
{
  int row = blockIdx.x;
  const float* hr = h + (size_t)row * D_MODEL;
  float s = 0.f;
  for (int i = threadIdx.x; i < D_MODEL; i += 256) { float v = hr[i]; s = fmaf(v, v, s); }
  #pragma unroll
  for (int o = 32; o > 0; o >>= 1) s += __shfl_down(s, o);
  __shared__ float red[4];
  int lane = threadIdx.x & 63, wid = threadIdx.x >> 6;
  if (lane == 0) red[wid] = s;
  __syncthreads();
  float total = red[0] + red[1] + red[2] + red[3];
  float scale = rsqrtf(total * (1.f / D_MODEL) + 1e-5f);
  unsigned short* ur = u + (size_t)row * D_MODEL;
  for (int i = threadIdx.x; i < D_MODEL; i += 256) ur[i] = f2bf(hr[i] * scale * w[i]);
}

// ---------------- weight transpose+convert: W[K][N] f32 -> WT[N][K] bf16 ----------------
__global__ __launch_bounds__(256) void wtrans_kernel(
    const float* __restrict__ W, unsigned short* __restrict__ WT, int K, int N)
{
  __shared__ float t[64][65];
  const int k0 = blockIdx.y * 64, n0 = blockIdx.x * 64;
  const int tc = (threadIdx.x & 15) << 2;   // 0..60 step 4
  const int tr = threadIdx.x >> 4;          // 0..15
  #pragma unroll
  for (int i = 0; i < 4; ++i) {
    int r = tr + (i << 4);
    float4 v = *(const float4*)(W + (size_t)(k0 + r) * N + n0 + tc);
    t[r][tc + 0] = v.x; t[r][tc + 1] = v.y; t[r][tc + 2] = v.z; t[r][tc + 3] = v.w;
  }
  __syncthreads();
  #pragma unroll
  for (int i = 0; i < 4; ++i) {
    int rr = tr + (i << 4);   // n within tile
    ushort4 o;
    o.x = f2bf(t[tc + 0][rr]);
    o.y = f2bf(t[tc + 1][rr]);
    o.z = f2bf(t[tc + 2][rr]);
    o.w = f2bf(t[tc + 3][rr]);
    *(ushort4*)(WT + (size_t)(n0 + rr) * K + k0 + tc) = o;
  }
}

// ---------------- bf16 MFMA GEMM: C[M,N] f32 = A[M,K]bf16 @ BT[N,K]^T + bias (+resid) ----
// tile 128x128, BK=32, 256 threads = 4 waves (2x2), each wave 64x64 = 4x4 frags.
__global__ __launch_bounds__(256) void gemm_bf16(
    const unsigned short* __restrict__ A, int lda,
    const unsigned short* __restrict__ BT, int ldb,
    const float* __restrict__ bias,
    const float* resid, int ldr,
    float* __restrict__ C, int ldc, int K)
{
  __shared__ unsigned short As[128 * 32];
  __shared__ unsigned short Bs[128 * 32];
  const int tid  = threadIdx.x;
  const int wave = tid >> 6;
  const int lane = tid & 63;
  const int bm = blockIdx.y * 128;
  const int bn = blockIdx.x * 128;
  const int wr = (wave >> 1) * 64;
  const int wc = (wave & 1) * 64;
  const int srow = lane >> 2;          // 0..15 within 16-row chunk
  const int scol = (lane & 3) * 8;     // bf16 element offset (16B)

  f32x4 acc[4][4];
  #pragma unroll
  for (int m = 0; m < 4; ++m)
    #pragma unroll
    for (int n = 0; n < 4; ++n)
      acc[m][n] = (f32x4){0.f, 0.f, 0.f, 0.f};

  for (int k0 = 0; k0 < K; k0 += 32) {
    #pragma unroll
    for (int i = 0; i < 2; ++i) {
      int c = wave + i * 4;            // chunk 0..7 (16 rows each)
      int row = c * 16 + srow;
      gload_lds16(A  + (size_t)(bm + row) * lda + k0 + scol, &As[c * 512]);
      gload_lds16(BT + (size_t)(bn + row) * ldb + k0 + scol, &Bs[c * 512]);
    }
    __syncthreads();
    bf16x8 af[4], bfr[4];
    #pragma unroll
    for (int m = 0; m < 4; ++m)
      af[m] = *(const bf16x8*)&As[(wr + m * 16 + (lane & 15)) * 32 + (lane >> 4) * 8];
    #pragma unroll
    for (int n = 0; n < 4; ++n)
      bfr[n] = *(const bf16x8*)&Bs[(wc + n * 16 + (lane & 15)) * 32 + (lane >> 4) * 8];
    #pragma unroll
    for (int m = 0; m < 4; ++m)
      #pragma unroll
      for (int n = 0; n < 4; ++n)
        acc[m][n] = __builtin_amdgcn_mfma_f32_16x16x32_bf16(af[m], bfr[n], acc[m][n], 0, 0, 0);
    __syncthreads();
  }

  const int rbase = (lane >> 4) * 4;
  const int cbase = lane & 15;
  #pragma unroll
  for (int m = 0; m < 4; ++m) {
    #pragma unroll
    for (int n = 0; n < 4; ++n) {
      const int col = bn + wc + n * 16 + cbase;
      const float bv = bias[col];
      #pragma unroll
      for (int r = 0; r < 4; ++r) {
        const int row = bm + wr + m * 16 + rbase + r;
        float v = acc[m][n][r] + bv;
        if (resid) v += resid[(size_t)row * ldr + col];
        C[(size_t)row * ldc + col] = v;
      }
    }
  }
}

// ---------------- depthwise causal conv (K=4) + silu: xz[:, :4096] -> xa ----------------
__global__ __launch_bounds__(256) void conv_silu_kernel(
    const float* __restrict__ xz, const float* __restrict__ cw,
    const float* __restrict__ cb, float* __restrict__ xa)
{
  int idx = blockIdx.x * 256 + threadIdx.x;  // over 1024*4096
  int e = idx & (EDIM - 1);
  int row = idx >> 12;                        // b*256 + l
  int l = row & (LSEQ - 1);
  float4 w = *(const float4*)(cw + (size_t)e * 4);
  const float* base = xz + (size_t)row * 8192 + e;
  float acc = cb[e];
  acc = fmaf(w.w, base[0], acc);
  if (l >= 1) acc = fmaf(w.z, base[-8192], acc);
  if (l >= 2) acc = fmaf(w.y, base[-2 * 8192], acc);
  if (l >= 3) acc = fmaf(w.x, base[-3 * 8192], acc);
  xa[idx] = silu_f(acc);
}

// ---------------- dbc = xa @ W_x  (1024 x 4096 x 34) ----------------
__global__ __launch_bounds__(256) void dbc_kernel(
    const float* __restrict__ xa, const float* __restrict__ Wx, float* __restrict__ dbc)
{
  int row = blockIdx.x;
  const float* ar = xa + (size_t)row * EDIM;
  float acc[34];
  #pragma unroll
  for (int j = 0; j < 34; ++j) acc[j] = 0.f;
  for (int k = threadIdx.x; k < EDIM; k += 256) {
    float av = ar[k];
    const float* wr = Wx + (size_t)k * 34;
    #pragma unroll
    for (int j = 0; j < 34; ++j) acc[j] = fmaf(av, wr[j], acc[j]);
  }
  __shared__ float red[34][4];
  int lane = threadIdx.x & 63, wid = threadIdx.x >> 6;
  #pragma unroll
  for (int j = 0; j < 34; ++j) {
    float v = acc[j];
    #pragma unroll
    for (int o = 32; o > 0; o >>= 1) v += __shfl_down(v, o);
    if (lane == 0) red[j][wid] = v;
  }
  __syncthreads();
  if (threadIdx.x < 34)
    dbc[(size_t)row * 34 + threadIdx.x] =
        red[threadIdx.x][0] + red[threadIdx.x][1] + red[threadIdx.x][2] + red[threadIdx.x][3];
}

// ---------------- dt = softplus(dbc[:, :2] @ W_dt + b_dt) ----------------
__global__ __launch_bounds__(256) void dtk_kernel(
    const float* __restrict__ dbc, const float* __restrict__ Wdt,
    const float* __restrict__ bdt, float* __restrict__ dtb)
{
  int idx = blockIdx.x * 256 + threadIdx.x;  // over 1024*4096
  int e = idx & (EDIM - 1);
  int row = idx >> 12;
  float d0 = dbc[(size_t)row * 34 + 0], d1 = dbc[(size_t)row * 34 + 1];
  float v = fmaf(d1, Wdt[EDIM + e], fmaf(d0, Wdt[e], bdt[e]));
  dtb[idx] = (v > 20.f) ? v : log1pf(expf(v));
}

// ---------------- selective scan, fused epilogue, bf16 y output ----------------
// grid = 256 blocks (b * 64 chunks), block = 256 = 4 waves.
// wave covers 16 channels x 4 n-groups (lane = ch + 16*g).
__global__ __launch_bounds__(256) void scan_kernel(
    const float* __restrict__ xz, const float* __restrict__ xa,
    const float* __restrict__ dtb, const float* __restrict__ dbc,
    const float* __restrict__ Alog, const float* __restrict__ Dpp,
    unsigned short* __restrict__ ybf)
{
  const int b = blockIdx.x >> 6;
  const int chunk = blockIdx.x & 63;
  const int wave = threadIdx.x >> 6;
  const int lane = threadIdx.x & 63;
  const int ch = lane & 15;
  const int g = lane >> 4;
  const int e = chunk * 64 + wave * 16 + ch;

  float Aa[4], hh[4];
  #pragma unroll
  for (int j = 0; j < 4; ++j) {
    Aa[j] = -expf(Alog[(size_t)e * 16 + g * 4 + j]);
    hh[j] = 0.f;
  }
  const float dpe = Dpp[e];

  for (int t = 0; t < LSEQ; ++t) {
    const int row = (b << 8) + t;
    float dta = dtb[(size_t)row * EDIM + e];
    float xav = xa[(size_t)row * EDIM + e];
    float zv  = xz[(size_t)row * 8192 + EDIM + e];
    const float* dr = dbc + (size_t)row * 34;
    float dtxa = dta * xav;
    float part = 0.f;
    #pragma unroll
    for (int j = 0; j < 4; ++j) {
      float da = __expf(dta * Aa[j]);
      hh[j] = fmaf(da, hh[j], dtxa * dr[2 + g * 4 + j]);
      part = fmaf(hh[j], dr[18 + g * 4 + j], part);
    }
    part += __shfl_xor(part, 16);
    part += __shfl_xor(part, 32);
    if (g == 0) {
      float yv = fmaf(dpe, xav, part);
      ybf[(size_t)row * EDIM + e] = f2bf(yv * silu_f(zv));
    }
  }
}

// ---------------- small head GEMMs ----------------
__global__ __launch_bounds__(256) void head_gemm_kernel(
    const float* __restrict__ in, int row_stride,
    const float* __restrict__ W, const float* __restrict__ bias,
    float* __restrict__ outp, int K, int N, int act)
{
  __shared__ float sIn[2048];
  const float* inr = in + (size_t)blockIdx.y * row_stride;
  for (int k = threadIdx.x; k < K; k += 256) sIn[k] = inr[k];
  __syncthreads();
  int j = blockIdx.x * 256 + threadIdx.x;
  float acc = bias[j];
  #pragma unroll 4
  for (int k = 0; k < K; ++k)
    acc = fmaf(sIn[k], W[(size_t)k * N + j], acc);
  if (act == 1) acc = silu_f(acc);
  else if (act == 2) acc = (acc > 0.f) ? acc : 0.01f * acc;
  outp[(size_t)blockIdx.y * N + j] = acc;
}

__global__ __launch_bounds__(256) void head_final_kernel(
    const float* __restrict__ g2, const float* __restrict__ W,
    const float* __restrict__ bb, float* __restrict__ out)
{
  int b_idx = threadIdx.x >> 6;   // 0..3
  int lane = threadIdx.x & 63;
  float s = 0.f;
  #pragma unroll
  for (int i = 0; i < 4; ++i) {
    int k = lane + i * 64;
    s = fmaf(g2[b_idx * 256 + k], W[k], s);
  }
  #pragma unroll
  for (int o = 32; o > 0; o >>= 1) s += __shfl_down(s, o);
  if (lane == 0) out[b_idx] = 1.f / (1.f + __expf(-(s + bb[0])));
}

extern "C" void kernel_launch(void* const* d_in, const int* in_sizes, int n_in,
                              void* d_out, int out_size, void* d_ws, size_t ws_size,
                              hipStream_t stream)
{
  const float* x      = (const float*)d_in[0];
  const float* W_emb  = (const float*)d_in[1];
  const float* b_emb  = (const float*)d_in[2];
  const float* norm_w = (const float*)d_in[3];
  const float* W_in   = (const float*)d_in[4];
  const float* b_in   = (const float*)d_in[5];
  const float* conv_w = (const float*)d_in[6];
  const float* conv_b = (const float*)d_in[7];
  const float* W_x    = (const float*)d_in[8];
  const float* W_dt   = (const float*)d_in[9];
  const float* b_dt   = (const float*)d_in[10];
  const float* A_log  = (const float*)d_in[11];
  const float* Dp     = (const float*)d_in[12];
  const float* W_out  = (const float*)d_in[13];
  const float* b_out  = (const float*)d_in[14];
  const float* W_f    = (const float*)d_in[15];
  const float* b_f    = (const float*)d_in[16];
  const float* W_h1   = (const float*)d_in[17];
  const float* b_h1   = (const float*)d_in[18];
  const float* W_h2   = (const float*)d_in[19];
  const float* b_h2   = (const float*)d_in[20];
  const float* W_h3   = (const float*)d_in[21];
  const float* b_h3   = (const float*)d_in[22];
  float* out = (float*)d_out;

  // workspace layout
  char* ws = (char*)d_ws;
  float*          h   = (float*)ws;                 ws += (size_t)1024 * 2048 * 4;  //  8 MB
  unsigned short* ubf = (unsigned short*)ws;        ws += (size_t)1024 * 2048 * 2;  //  4 MB
  float*          xz  = (float*)ws;                 ws += (size_t)1024 * 8192 * 4;  // 32 MB
  float*          xa  = (float*)ws;                 ws += (size_t)1024 * 4096 * 4;  // 16 MB
  float*          dtb = (float*)ws;                 ws += (size_t)1024 * 4096 * 4;  // 16 MB
  float*          dbc = (float*)ws;                 ws += (size_t)1024 * 40 * 4;    // pad 40
  unsigned short* ybf = (unsigned short*)ws;        ws += (size_t)1024 * 4096 * 2;  //  8 MB
  unsigned short* WT  = (unsigned short*)ws;        ws += (size_t)8192 * 2048 * 2;  // 33.6 MB
  float*          fb  = (float*)ws;                 ws += 4096 * 4;
  float*          g1b = (float*)ws;                 ws += 2048 * 4;
  float*          g2b = (float*)ws;                 ws += 1024 * 4;

  embed_kernel<<<dim3(D_MODEL / 256, 1024), 256, 0, stream>>>(x, W_emb, b_emb, h);

  for (int i = 0; i < NLAYER; ++i) {
    const float* Wi  = W_in  + (size_t)i * 2048 * 8192;
    const float* bi  = b_in  + (size_t)i * 8192;
    const float* cwi = conv_w + (size_t)i * 4096 * 4;
    const float* cbi = conv_b + (size_t)i * 4096;
    const float* Wxi = W_x   + (size_t)i * 4096 * 34;
    const float* Wdti= W_dt  + (size_t)i * 2 * 4096;
    const float* bdti= b_dt  + (size_t)i * 4096;
    const float* Ali = A_log + (size_t)i * 4096 * 16;
    const float* Dpi = Dp    + (size_t)i * 4096;
    const float* Woi = W_out + (size_t)i * 4096 * 2048;
    const float* boi = b_out + (size_t)i * 2048;
    const float* nwi = norm_w + (size_t)i * 2048;

    rmsnorm_kernel<<<1024, 256, 0, stream>>>(h, nwi, ubf);
    // WT = W_in^T (8192 x 2048 bf16)
    wtrans_kernel<<<dim3(8192 / 64, 2048 / 64), 256, 0, stream>>>(Wi, WT, 2048, 8192);
    // xz = ubf @ WT^T + b_in   (M=1024, N=8192, K=2048)
    gemm_bf16<<<dim3(8192 / 128, 1024 / 128), 256, 0, stream>>>(
        ubf, 2048, WT, 2048, bi, nullptr, 0, xz, 8192, 2048);
    conv_silu_kernel<<<(1024 * 4096) / 256, 256, 0, stream>>>(xz, cwi, cbi, xa);
    dbc_kernel<<<1024, 256, 0, stream>>>(xa, Wxi, dbc);
    dtk_kernel<<<(1024 * 4096) / 256, 256, 0, stream>>>(dbc, Wdti, bdti, dtb);
    scan_kernel<<<256, 256, 0, stream>>>(xz, xa, dtb, dbc, Ali, Dpi, ybf);
    // WT = W_out^T (2048 x 4096 bf16)
    wtrans_kernel<<<dim3(2048 / 64, 4096 / 64), 256, 0, stream>>>(Woi, WT, 4096, 2048);
    // h = h + ybf @ WT^T + b_out   (M=1024, N=2048, K=4096)
    gemm_bf16<<<dim3(2048 / 128, 1024 / 128), 256, 0, stream>>>(
        ybf, 4096, WT, 4096, boi, h, 2048, h, 2048, 4096);
  }

  head_gemm_kernel<<<dim3(1024 / 256, BATCH), 256, 0, stream>>>(
      h + (size_t)255 * 2048, 256 * 2048, W_f, b_f, fb, 2048, 1024, 0);
  head_gemm_kernel<<<dim3(512 / 256, BATCH), 256, 0, stream>>>(
      fb, 1024, W_h1, b_h1, g1b, 1024, 512, 1);
  head_gemm_kernel<<<dim3(256 / 256, BATCH), 256, 0, stream>>>(
      g1b, 512, W_h2, b_h2, g2b, 512, 256, 2);
  head_final_kernel<<<1, 256, 0, stream>>>(g2b, W_h3, b_h3, out);
}

// Round 3
// 2916.363 us; speedup vs baseline: 2.3856x; 1.1103x over previous
//
#include <hip/hip_runtime.h>
#include <hip/hip_bf16.h>
#include <math.h>

#define D_MODEL 2048
#define EDIM    4096
#define NSTATE  16
#define LSEQ    256
#define BATCH   4
#define NLAYER  6
#define FDIM    80

typedef __attribute__((ext_vector_type(8))) short bf16x8;
typedef __attribute__((ext_vector_type(4))) float f32x4;

__device__ __forceinline__ float silu_f(float x) { return x / (1.f + __expf(-x)); }

// RNE float -> bf16 bits
__device__ __forceinline__ unsigned short f2bf(float f) {
  unsigned u = __float_as_uint(f);
  unsigned r = u + 0x7fffu + ((u >> 16) & 1u);
  return (unsigned short)(r >> 16);
}

__device__ __forceinline__ void gload_lds16(const void* g, void* l) {
  __builtin_amdgcn_global_load_lds(
      (const __attribute__((address_space(1))) unsigned int*)g,
      (__attribute__((address_space(3))) unsigned int*)l, 16, 0, 0);
}

// ---------------- embedding: h[b,l,:] = x[b,:,l]^T @ W_emb + b_emb ----------------
__global__ __launch_bounds__(256) void embed_kernel(
    const float* __restrict__ x, const float* __restrict__ W,
    const float* __restrict__ bias, float* __restrict__ h)
{
  int col = blockIdx.x * 256 + threadIdx.x;   // 0..2047
  int row = blockIdx.y;                        // 0..1023  (b*256 + l)
  int b = row >> 8, l = row & 255;
  const float* xp = x + (size_t)b * FDIM * LSEQ + l;
  float acc = bias[col];
  #pragma unroll 8
  for (int f = 0; f < FDIM; ++f)
    acc = fmaf(xp[(size_t)f * LSEQ], W[(size_t)f * D_MODEL + col], acc);
  h[(size_t)row * D_MODEL + col] = acc;
}

// ---------------- rmsnorm: u_bf16 = h * rsqrt(mean(h^2)+eps) * w ----------------
__global__ __launch_bounds__(256) void rmsnorm_kernel(
    const float* __restrict__ h, const float* __restrict__ w, unsigned short* __restrict__ u)
{
  int row = blockIdx.x;
  const float* hr = h + (size_t)row * D_MODEL;
  float s = 0.f;
  for (int i = threadIdx.x; i < D_MODEL; i += 256) { float v = hr[i]; s = fmaf(v, v, s); }
  #pragma unroll
  for (int o = 32; o > 0; o >>= 1) s += __shfl_down(s, o);
  __shared__ float red[4];
  int lane = threadIdx.x & 63, wid = threadIdx.x >> 6;
  if (lane == 0) red[wid] = s;
  __syncthreads();
  float total = red[0] + red[1] + red[2] + red[3];
  float scale = rsqrtf(total * (1.f / D_MODEL) + 1e-5f);
  unsigned short* ur = u + (size_t)row * D_MODEL;
  for (int i = threadIdx.x; i < D_MODEL; i += 256) ur[i] = f2bf(hr[i] * scale * w[i]);
}

// ---------------- weight transpose+convert: W[K][N] f32 -> WT[N][K] bf16 ----------------
__global__ __launch_bounds__(256) void wtrans_kernel(
    const float* __restrict__ W, unsigned short* __restrict__ WT, int K, int N)
{
  __shared__ float t[64][65];
  const int k0 = blockIdx.y * 64, n0 = blockIdx.x * 64;
  const int tc = (threadIdx.x & 15) << 2;   // 0..60 step 4
  const int tr = threadIdx.x >> 4;          // 0..15
  #pragma unroll
  for (int i = 0; i < 4; ++i) {
    int r = tr + (i << 4);
    float4 v = *(const float4*)(W + (size_t)(k0 + r) * N + n0 + tc);
    t[r][tc + 0] = v.x; t[r][tc + 1] = v.y; t[r][tc + 2] = v.z; t[r][tc + 3] = v.w;
  }
  __syncthreads();
  #pragma unroll
  for (int i = 0; i < 4; ++i) {
    int rr = tr + (i << 4);   // n within tile
    ushort4 o;
    o.x = f2bf(t[tc + 0][rr]);
    o.y = f2bf(t[tc + 1][rr]);
    o.z = f2bf(t[tc + 2][rr]);
    o.w = f2bf(t[tc + 3][rr]);
    *(ushort4*)(WT + (size_t)(n0 + rr) * K + k0 + tc) = o;
  }
}

// ---------------- bf16 MFMA GEMM: C[M,N] f32 = A[M,K]bf16 @ BT[N,K]^T + bias (+resid) ----
// tile 128xBN, BK=32, 256 threads = 4 waves (2x2), each wave 64 x BN/2.
template<int BN>
__global__ __launch_bounds__(256) void gemm_bf16(
    const unsigned short* __restrict__ A, int lda,
    const unsigned short* __restrict__ BT, int ldb,
    const float* __restrict__ bias,
    const float* resid, int ldr,
    float* __restrict__ C, int ldc, int K)
{
  constexpr int BM = 128;
  constexpr int FN = BN / 32;          // N-frags per wave: 128->4, 64->2
  __shared__ unsigned short As[BM * 32];
  __shared__ unsigned short Bs[BN * 32];
  const int tid  = threadIdx.x;
  const int wave = tid >> 6;
  const int lane = tid & 63;
  const int bm = blockIdx.y * BM;
  const int bn = blockIdx.x * BN;
  const int wr = (wave >> 1) * 64;
  const int wc = (wave & 1) * (BN / 2);
  const int srow = lane >> 2;          // 0..15 within 16-row chunk
  const int scol = (lane & 3) * 8;     // bf16 element offset (16B)

  f32x4 acc[4][FN];
  #pragma unroll
  for (int m = 0; m < 4; ++m)
    #pragma unroll
    for (int n = 0; n < FN; ++n)
      acc[m][n] = (f32x4){0.f, 0.f, 0.f, 0.f};

  for (int k0 = 0; k0 < K; k0 += 32) {
    #pragma unroll
    for (int i = 0; i < BM / 64; ++i) {
      int c = wave + i * 4;            // 16-row chunk
      gload_lds16(A + (size_t)(bm + c * 16 + srow) * lda + k0 + scol, &As[c * 512]);
    }
    #pragma unroll
    for (int i = 0; i < BN / 64; ++i) {
      int c = wave + i * 4;
      gload_lds16(BT + (size_t)(bn + c * 16 + srow) * ldb + k0 + scol, &Bs[c * 512]);
    }
    __syncthreads();
    bf16x8 af[4], bfr[FN];
    #pragma unroll
    for (int m = 0; m < 4; ++m)
      af[m] = *(const bf16x8*)&As[(wr + m * 16 + (lane & 15)) * 32 + (lane >> 4) * 8];
    #pragma unroll
    for (int n = 0; n < FN; ++n)
      bfr[n] = *(const bf16x8*)&Bs[(wc + n * 16 + (lane & 15)) * 32 + (lane >> 4) * 8];
    #pragma unroll
    for (int m = 0; m < 4; ++m)
      #pragma unroll
      for (int n = 0; n < FN; ++n)
        acc[m][n] = __builtin_amdgcn_mfma_f32_16x16x32_bf16(af[m], bfr[n], acc[m][n], 0, 0, 0);
    __syncthreads();
  }

  const int rbase = (lane >> 4) * 4;
  const int cbase = lane & 15;
  #pragma unroll
  for (int m = 0; m < 4; ++m) {
    #pragma unroll
    for (int n = 0; n < FN; ++n) {
      const int col = bn + wc + n * 16 + cbase;
      const float bv = bias[col];
      #pragma unroll
      for (int r = 0; r < 4; ++r) {
        const int row = bm + wr + m * 16 + rbase + r;
        float v = acc[m][n][r] + bv;
        if (resid) v += resid[(size_t)row * ldr + col];
        C[(size_t)row * ldc + col] = v;
      }
    }
  }
}

// ---------------- fused depthwise conv(K=4)+silu -> xa, and dbc = xa @ W_x ----------------
// one block per row (1024 blocks, 256 threads); each thread handles 16 channels.
__global__ __launch_bounds__(256) void conv_dbc_kernel(
    const float* __restrict__ xz, const float* __restrict__ cw,
    const float* __restrict__ cb, const float* __restrict__ Wx,
    float* __restrict__ xa, float* __restrict__ dbc)
{
  const int row = blockIdx.x;          // b*256 + l
  const int l = row & (LSEQ - 1);
  const int tid = threadIdx.x;
  float acc[34];
  #pragma unroll
  for (int j = 0; j < 34; ++j) acc[j] = 0.f;
  const float* base_row = xz + (size_t)row * 8192;
  for (int k = 0; k < 16; ++k) {
    const int e = k * 256 + tid;
    float4 w = *(const float4*)(cw + (size_t)e * 4);
    const float* base = base_row + e;
    float a = cb[e];
    a = fmaf(w.w, base[0], a);
    if (l >= 1) a = fmaf(w.z, base[-8192], a);
    if (l >= 2) a = fmaf(w.y, base[-2 * 8192], a);
    if (l >= 3) a = fmaf(w.x, base[-3 * 8192], a);
    a = silu_f(a);
    xa[(size_t)row * EDIM + e] = a;
    const float* wr = Wx + (size_t)e * 34;
    #pragma unroll
    for (int j = 0; j < 34; ++j) acc[j] = fmaf(a, wr[j], acc[j]);
  }
  __shared__ float red[34][4];
  const int lane = tid & 63, wid = tid >> 6;
  #pragma unroll
  for (int j = 0; j < 34; ++j) {
    float v = acc[j];
    #pragma unroll
    for (int o = 32; o > 0; o >>= 1) v += __shfl_down(v, o);
    if (lane == 0) red[j][wid] = v;
  }
  __syncthreads();
  if (tid < 34)
    dbc[(size_t)row * 34 + tid] = red[tid][0] + red[tid][1] + red[tid][2] + red[tid][3];
}

// ---------------- selective scan: dt inline, depth-4 reg prefetch, fused epilogue --------
// grid = 512 blocks (4 b x 128 chunks of 32 channels), 256 threads = 4 waves.
// lane = ch(0..7) + 8*g(0..7); each lane owns 2 states of channel e.
struct ScanIn { float x[4], z[4], d0[4], d1[4], B0[4], B1[4], C0[4], C1[4]; };

__device__ __forceinline__ void scan_load(
    ScanIn& s, const float* xap, const float* zp, const float* dp, int t0, int g)
{
  #pragma unroll
  for (int u = 0; u < 4; ++u) {
    const int t = t0 + u;
    s.x[u] = xap[(size_t)t * EDIM];
    s.z[u] = zp[(size_t)t * 8192];
    const float* dr = dp + (size_t)t * 34;
    s.d0[u] = dr[0];           s.d1[u] = dr[1];
    s.B0[u] = dr[2 + 2 * g];   s.B1[u] = dr[3 + 2 * g];
    s.C0[u] = dr[18 + 2 * g];  s.C1[u] = dr[19 + 2 * g];
  }
}

__device__ __forceinline__ void scan_step(
    const ScanIn& s, float& h0, float& h1,
    float w0, float w1, float bde, float Aa0, float Aa1, float dpe,
    int g, unsigned short* yp, int t0)
{
  #pragma unroll
  for (int u = 0; u < 4; ++u) {
    float v = fmaf(s.d1[u], w1, fmaf(s.d0[u], w0, bde));
    float dta = (v > 20.f) ? v : log1pf(__expf(v));
    float dtxa = dta * s.x[u];
    h0 = fmaf(__expf(dta * Aa0), h0, dtxa * s.B0[u]);
    h1 = fmaf(__expf(dta * Aa1), h1, dtxa * s.B1[u]);
    float part = fmaf(h0, s.C0[u], h1 * s.C1[u]);
    part += __shfl_xor(part, 8);
    part += __shfl_xor(part, 16);
    part += __shfl_xor(part, 32);
    if (g == 0) {
      float yv = fmaf(dpe, s.x[u], part);
      yp[(size_t)(t0 + u) * EDIM] = f2bf(yv * silu_f(s.z[u]));
    }
  }
}

__global__ __launch_bounds__(256) void scan_kernel(
    const float* __restrict__ xz, const float* __restrict__ xa,
    const float* __restrict__ dbc,
    const float* __restrict__ Wdt, const float* __restrict__ bdt,
    const float* __restrict__ Alog, const float* __restrict__ Dpp,
    unsigned short* __restrict__ ybf)
{
  const int b = blockIdx.x >> 7;
  const int chunk = blockIdx.x & 127;
  const int wave = threadIdx.x >> 6;
  const int lane = threadIdx.x & 63;
  const int ch = lane & 7;
  const int g = lane >> 3;
  const int e = chunk * 32 + wave * 8 + ch;

  const float w0 = Wdt[e], w1 = Wdt[EDIM + e], bde = bdt[e];
  const float Aa0 = -expf(Alog[(size_t)e * 16 + g * 2]);
  const float Aa1 = -expf(Alog[(size_t)e * 16 + g * 2 + 1]);
  const float dpe = Dpp[e];
  float h0 = 0.f, h1 = 0.f;

  const float* xap = xa + (size_t)(b << 8) * EDIM + e;
  const float* zp  = xz + (size_t)(b << 8) * 8192 + EDIM + e;
  const float* dp  = dbc + (size_t)(b << 8) * 34;
  unsigned short* yp = ybf + (size_t)(b << 8) * EDIM + e;

  ScanIn sa, sb;
  scan_load(sa, xap, zp, dp, 0, g);
  for (int t0 = 0; t0 < LSEQ; t0 += 8) {
    scan_load(sb, xap, zp, dp, t0 + 4, g);
    scan_step(sa, h0, h1, w0, w1, bde, Aa0, Aa1, dpe, g, yp, t0);
    if (t0 + 8 < LSEQ) scan_load(sa, xap, zp, dp, t0 + 8, g);
    scan_step(sb, h0, h1, w0, w1, bde, Aa0, Aa1, dpe, g, yp, t0 + 4);
  }
}

// ---------------- small head GEMMs ----------------
__global__ __launch_bounds__(256) void head_gemm_kernel(
    const float* __restrict__ in, int row_stride,
    const float* __restrict__ W, const float* __restrict__ bias,
    float* __restrict__ outp, int K, int N, int act)
{
  __shared__ float sIn[2048];
  const float* inr = in + (size_t)blockIdx.y * row_stride;
  for (int k = threadIdx.x; k < K; k += 256) sIn[k] = inr[k];
  __syncthreads();
  int j = blockIdx.x * 256 + threadIdx.x;
  float acc = bias[j];
  #pragma unroll 4
  for (int k = 0; k < K; ++k)
    acc = fmaf(sIn[k], W[(size_t)k * N + j], acc);
  if (act == 1) acc = silu_f(acc);
  else if (act == 2) acc = (acc > 0.f) ? acc : 0.01f * acc;
  outp[(size_t)blockIdx.y * N + j] = acc;
}

__global__ __launch_bounds__(256) void head_final_kernel(
    const float* __restrict__ g2, const float* __restrict__ W,
    const float* __restrict__ bb, float* __restrict__ out)
{
  int b_idx = threadIdx.x >> 6;   // 0..3
  int lane = threadIdx.x & 63;
  float s = 0.f;
  #pragma unroll
  for (int i = 0; i < 4; ++i) {
    int k = lane + i * 64;
    s = fmaf(g2[b_idx * 256 + k], W[k], s);
  }
  #pragma unroll
  for (int o = 32; o > 0; o >>= 1) s += __shfl_down(s, o);
  if (lane == 0) out[b_idx] = 1.f / (1.f + __expf(-(s + bb[0])));
}

extern "C" void kernel_launch(void* const* d_in, const int* in_sizes, int n_in,
                              void* d_out, int out_size, void* d_ws, size_t ws_size,
                              hipStream_t stream)
{
  const float* x      = (const float*)d_in[0];
  const float* W_emb  = (const float*)d_in[1];
  const float* b_emb  = (const float*)d_in[2];
  const float* norm_w = (const float*)d_in[3];
  const float* W_in   = (const float*)d_in[4];
  const float* b_in   = (const float*)d_in[5];
  const float* conv_w = (const float*)d_in[6];
  const float* conv_b = (const float*)d_in[7];
  const float* W_x    = (const float*)d_in[8];
  const float* W_dt   = (const float*)d_in[9];
  const float* b_dt   = (const float*)d_in[10];
  const float* A_log  = (const float*)d_in[11];
  const float* Dp     = (const float*)d_in[12];
  const float* W_out  = (const float*)d_in[13];
  const float* b_out  = (const float*)d_in[14];
  const float* W_f    = (const float*)d_in[15];
  const float* b_f    = (const float*)d_in[16];
  const float* W_h1   = (const float*)d_in[17];
  const float* b_h1   = (const float*)d_in[18];
  const float* W_h2   = (const float*)d_in[19];
  const float* b_h2   = (const float*)d_in[20];
  const float* W_h3   = (const float*)d_in[21];
  const float* b_h3   = (const float*)d_in[22];
  float* out = (float*)d_out;

  // workspace layout
  char* ws = (char*)d_ws;
  float*          h   = (float*)ws;                 ws += (size_t)1024 * 2048 * 4;  //  8 MB
  unsigned short* ubf = (unsigned short*)ws;        ws += (size_t)1024 * 2048 * 2;  //  4 MB
  float*          xz  = (float*)ws;                 ws += (size_t)1024 * 8192 * 4;  // 32 MB
  float*          xa  = (float*)ws;                 ws += (size_t)1024 * 4096 * 4;  // 16 MB
  float*          dbc = (float*)ws;                 ws += (size_t)1024 * 40 * 4;
  unsigned short* ybf = (unsigned short*)ws;        ws += (size_t)1024 * 4096 * 2;  //  8 MB
  unsigned short* WT  = (unsigned short*)ws;        ws += (size_t)8192 * 2048 * 2;  // 33.6 MB
  float*          fb  = (float*)ws;                 ws += 4096 * 4;
  float*          g1b = (float*)ws;                 ws += 2048 * 4;
  float*          g2b = (float*)ws;                 ws += 1024 * 4;

  embed_kernel<<<dim3(D_MODEL / 256, 1024), 256, 0, stream>>>(x, W_emb, b_emb, h);

  for (int i = 0; i < NLAYER; ++i) {
    const float* Wi  = W_in  + (size_t)i * 2048 * 8192;
    const float* bi  = b_in  + (size_t)i * 8192;
    const float* cwi = conv_w + (size_t)i * 4096 * 4;
    const float* cbi = conv_b + (size_t)i * 4096;
    const float* Wxi = W_x   + (size_t)i * 4096 * 34;
    const float* Wdti= W_dt  + (size_t)i * 2 * 4096;
    const float* bdti= b_dt  + (size_t)i * 4096;
    const float* Ali = A_log + (size_t)i * 4096 * 16;
    const float* Dpi = Dp    + (size_t)i * 4096;
    const float* Woi = W_out + (size_t)i * 4096 * 2048;
    const float* boi = b_out + (size_t)i * 2048;
    const float* nwi = norm_w + (size_t)i * 2048;

    rmsnorm_kernel<<<1024, 256, 0, stream>>>(h, nwi, ubf);
    // WT = W_in^T (8192 x 2048 bf16)
    wtrans_kernel<<<dim3(8192 / 64, 2048 / 64), 256, 0, stream>>>(Wi, WT, 2048, 8192);
    // xz = ubf @ WT^T + b_in   (M=1024, N=8192, K=2048)
    gemm_bf16<128><<<dim3(8192 / 128, 1024 / 128), 256, 0, stream>>>(
        ubf, 2048, WT, 2048, bi, nullptr, 0, xz, 8192, 2048);
    conv_dbc_kernel<<<1024, 256, 0, stream>>>(xz, cwi, cbi, Wxi, xa, dbc);
    scan_kernel<<<512, 256, 0, stream>>>(xz, xa, dbc, Wdti, bdti, Ali, Dpi, ybf);
    // WT = W_out^T (2048 x 4096 bf16)
    wtrans_kernel<<<dim3(2048 / 64, 4096 / 64), 256, 0, stream>>>(Woi, WT, 4096, 2048);
    // h = h + ybf @ WT^T + b_out   (M=1024, N=2048, K=4096), 256 blocks
    gemm_bf16<64><<<dim3(2048 / 64, 1024 / 128), 256, 0, stream>>>(
        ybf, 4096, WT, 4096, boi, h, 2048, h, 2048, 4096);
  }

  head_gemm_kernel<<<dim3(1024 / 256, BATCH), 256, 0, stream>>>(
      h + (size_t)255 * 2048, 256 * 2048, W_f, b_f, fb, 2048, 1024, 0);
  head_gemm_kernel<<<dim3(512 / 256, BATCH), 256, 0, stream>>>(
      fb, 1024, W_h1, b_h1, g1b, 1024, 512, 1);
  head_gemm_kernel<<<dim3(256 / 256, BATCH), 256, 0, stream>>>(
      g1b, 512, W_h2, b_h2, g2b, 512, 256, 2);
  head_final_kernel<<<1, 256, 0, stream>>>(g2b, W_h3, b_h3, out);
}

// Round 4
// 2902.062 us; speedup vs baseline: 2.3973x; 1.0049x over previous
//
#include <hip/hip_runtime.h>
#include <hip/hip_bf16.h>
#include <math.h>

#define D_MODEL 2048
#define EDIM    4096
#define NSTATE  16
#define LSEQ    256
#define BATCH   4
#define NLAYER  6
#define FDIM    80

typedef __attribute__((ext_vector_type(8))) short bf16x8;
typedef __attribute__((ext_vector_type(4))) float f32x4;

__device__ __forceinline__ float silu_f(float x) { return x / (1.f + __expf(-x)); }

// RNE float -> bf16 bits
__device__ __forceinline__ unsigned short f2bf(float f) {
  unsigned u = __float_as_uint(f);
  unsigned r = u + 0x7fffu + ((u >> 16) & 1u);
  return (unsigned short)(r >> 16);
}

__device__ __forceinline__ void gload_lds16(const void* g, void* l) {
  __builtin_amdgcn_global_load_lds(
      (const __attribute__((address_space(1))) unsigned int*)g,
      (__attribute__((address_space(3))) unsigned int*)l, 16, 0, 0);
}

// ---------------- embedding: h[b,l,:] = x[b,:,l]^T @ W_emb + b_emb ----------------
__global__ __launch_bounds__(256) void embed_kernel(
    const float* __restrict__ x, const float* __restrict__ W,
    const float* __restrict__ bias, float* __restrict__ h)
{
  int col = blockIdx.x * 256 + threadIdx.x;   // 0..2047
  int row = blockIdx.y;                        // 0..1023  (b*256 + l)
  int b = row >> 8, l = row & 255;
  const float* xp = x + (size_t)b * FDIM * LSEQ + l;
  float acc = bias[col];
  #pragma unroll 8
  for (int f = 0; f < FDIM; ++f)
    acc = fmaf(xp[(size_t)f * LSEQ], W[(size_t)f * D_MODEL + col], acc);
  h[(size_t)row * D_MODEL + col] = acc;
}

// ---------------- rmsnorm: u_bf16 = h * rsqrt(mean(h^2)+eps) * w ----------------
__global__ __launch_bounds__(256) void rmsnorm_kernel(
    const float* __restrict__ h, const float* __restrict__ w, unsigned short* __restrict__ u)
{
  int row = blockIdx.x;
  const float* hr = h + (size_t)row * D_MODEL;
  float s = 0.f;
  for (int i = threadIdx.x; i < D_MODEL; i += 256) { float v = hr[i]; s = fmaf(v, v, s); }
  #pragma unroll
  for (int o = 32; o > 0; o >>= 1) s += __shfl_down(s, o);
  __shared__ float red[4];
  int lane = threadIdx.x & 63, wid = threadIdx.x >> 6;
  if (lane == 0) red[wid] = s;
  __syncthreads();
  float total = red[0] + red[1] + red[2] + red[3];
  float scale = rsqrtf(total * (1.f / D_MODEL) + 1e-5f);
  unsigned short* ur = u + (size_t)row * D_MODEL;
  for (int i = threadIdx.x; i < D_MODEL; i += 256) ur[i] = f2bf(hr[i] * scale * w[i]);
}

// ---------------- weight transpose+convert: W[K][N] f32 -> WT[N][K] bf16 ----------------
__global__ __launch_bounds__(256) void wtrans_kernel(
    const float* __restrict__ W, unsigned short* __restrict__ WT, int K, int N)
{
  __shared__ float t[64][65];
  const int k0 = blockIdx.y * 64, n0 = blockIdx.x * 64;
  const int tc = (threadIdx.x & 15) << 2;   // 0..60 step 4
  const int tr = threadIdx.x >> 4;          // 0..15
  #pragma unroll
  for (int i = 0; i < 4; ++i) {
    int r = tr + (i << 4);
    float4 v = *(const float4*)(W + (size_t)(k0 + r) * N + n0 + tc);
    t[r][tc + 0] = v.x; t[r][tc + 1] = v.y; t[r][tc + 2] = v.z; t[r][tc + 3] = v.w;
  }
  __syncthreads();
  #pragma unroll
  for (int i = 0; i < 4; ++i) {
    int rr = tr + (i << 4);   // n within tile
    ushort4 o;
    o.x = f2bf(t[tc + 0][rr]);
    o.y = f2bf(t[tc + 1][rr]);
    o.z = f2bf(t[tc + 2][rr]);
    o.w = f2bf(t[tc + 3][rr]);
    *(ushort4*)(WT + (size_t)(n0 + rr) * K + k0 + tc) = o;
  }
}

// ---------------- bf16 MFMA GEMM: C[M,N] f32 = A[M,K]bf16 @ BT[N,K]^T + bias (+resid) ----
// tile 128xBN, BK=32, 256 threads = 4 waves (2x2), each wave 64 x BN/2.
// T3-minimum 2-phase: double-buffered LDS, ONE barrier per K-step, next-tile
// global_load_lds issued before current-tile ds_read+MFMA (overlap under compute).
// Correctness: compiler emits s_waitcnt vmcnt(0) lgkmcnt(0) before each s_barrier.
// T1: bijective XCD swizzle (nwg % 8 == 0 for all launches here).
template<int BN>
__global__ __launch_bounds__(256) void gemm_bf16(
    const unsigned short* __restrict__ A, int lda,
    const unsigned short* __restrict__ BT, int ldb,
    const float* __restrict__ bias,
    const float* resid, int ldr,
    float* __restrict__ C, int ldc, int K)
{
  constexpr int BM = 128;
  constexpr int FN = BN / 32;          // N-frags per wave: 128->4, 64->2
  __shared__ unsigned short As[2][BM * 32];
  __shared__ unsigned short Bs[2][BN * 32];
  const int tid  = threadIdx.x;
  const int wave = tid >> 6;
  const int lane = tid & 63;

  // XCD-aware swizzle: each XCD gets a contiguous chunk of flat tile space
  // (chunk spans one grid row -> all blocks on an XCD share the same A panel).
  const int nwg = gridDim.x * gridDim.y;
  const int cpx = nwg >> 3;
  int flat = blockIdx.y * gridDim.x + blockIdx.x;
  flat = (flat & 7) * cpx + (flat >> 3);
  const int bm = (flat / gridDim.x) * BM;
  const int bn = (flat % gridDim.x) * BN;

  const int wr = (wave >> 1) * 64;
  const int wc = (wave & 1) * (BN / 2);
  const int srow = lane >> 2;          // 0..15 within 16-row chunk
  const int scol = (lane & 3) * 8;     // bf16 element offset (16B)

  f32x4 acc[4][FN];
  #pragma unroll
  for (int m = 0; m < 4; ++m)
    #pragma unroll
    for (int n = 0; n < FN; ++n)
      acc[m][n] = (f32x4){0.f, 0.f, 0.f, 0.f};

  auto stage = [&](int buf, int k0) {
    #pragma unroll
    for (int i = 0; i < BM / 64; ++i) {
      int c = wave + i * 4;            // 16-row chunk
      gload_lds16(A + (size_t)(bm + c * 16 + srow) * lda + k0 + scol, &As[buf][c * 512]);
    }
    #pragma unroll
    for (int i = 0; i < BN / 64; ++i) {
      int c = wave + i * 4;
      gload_lds16(BT + (size_t)(bn + c * 16 + srow) * ldb + k0 + scol, &Bs[buf][c * 512]);
    }
  };

  stage(0, 0);
  const int nk = K >> 5;
  for (int t = 0; t < nk; ++t) {
    const int cur = t & 1;
    __syncthreads();                       // buf[cur] staged (vmcnt drained here)
    if (t + 1 < nk) stage(cur ^ 1, (t + 1) << 5);   // prefetch flies under MFMA
    bf16x8 af[4], bfr[FN];
    #pragma unroll
    for (int m = 0; m < 4; ++m)
      af[m] = *(const bf16x8*)&As[cur][(wr + m * 16 + (lane & 15)) * 32 + (lane >> 4) * 8];
    #pragma unroll
    for (int n = 0; n < FN; ++n)
      bfr[n] = *(const bf16x8*)&Bs[cur][(wc + n * 16 + (lane & 15)) * 32 + (lane >> 4) * 8];
    #pragma unroll
    for (int m = 0; m < 4; ++m)
      #pragma unroll
      for (int n = 0; n < FN; ++n)
        acc[m][n] = __builtin_amdgcn_mfma_f32_16x16x32_bf16(af[m], bfr[n], acc[m][n], 0, 0, 0);
  }

  const int rbase = (lane >> 4) * 4;
  const int cbase = lane & 15;
  #pragma unroll
  for (int m = 0; m < 4; ++m) {
    #pragma unroll
    for (int n = 0; n < FN; ++n) {
      const int col = bn + wc + n * 16 + cbase;
      const float bv = bias[col];
      #pragma unroll
      for (int r = 0; r < 4; ++r) {
        const int row = bm + wr + m * 16 + rbase + r;
        float v = acc[m][n][r] + bv;
        if (resid) v += resid[(size_t)row * ldr + col];
        C[(size_t)row * ldc + col] = v;
      }
    }
  }
}

// ---------------- fused depthwise conv(K=4)+silu -> xa, and dbc = xa @ W_x ----------------
// one block per row (1024 blocks, 256 threads); each thread handles 16 channels.
__global__ __launch_bounds__(256) void conv_dbc_kernel(
    const float* __restrict__ xz, const float* __restrict__ cw,
    const float* __restrict__ cb, const float* __restrict__ Wx,
    float* __restrict__ xa, float* __restrict__ dbc)
{
  const int row = blockIdx.x;          // b*256 + l
  const int l = row & (LSEQ - 1);
  const int tid = threadIdx.x;
  float acc[34];
  #pragma unroll
  for (int j = 0; j < 34; ++j) acc[j] = 0.f;
  const float* base_row = xz + (size_t)row * 8192;
  for (int k = 0; k < 16; ++k) {
    const int e = k * 256 + tid;
    float4 w = *(const float4*)(cw + (size_t)e * 4);
    const float* base = base_row + e;
    float a = cb[e];
    a = fmaf(w.w, base[0], a);
    if (l >= 1) a = fmaf(w.z, base[-8192], a);
    if (l >= 2) a = fmaf(w.y, base[-2 * 8192], a);
    if (l >= 3) a = fmaf(w.x, base[-3 * 8192], a);
    a = silu_f(a);
    xa[(size_t)row * EDIM + e] = a;
    const float* wr = Wx + (size_t)e * 34;
    #pragma unroll
    for (int j = 0; j < 34; ++j) acc[j] = fmaf(a, wr[j], acc[j]);
  }
  __shared__ float red[34][4];
  const int lane = tid & 63, wid = tid >> 6;
  #pragma unroll
  for (int j = 0; j < 34; ++j) {
    float v = acc[j];
    #pragma unroll
    for (int o = 32; o > 0; o >>= 1) v += __shfl_down(v, o);
    if (lane == 0) red[j][wid] = v;
  }
  __syncthreads();
  if (tid < 34)
    dbc[(size_t)row * 34 + tid] = red[tid][0] + red[tid][1] + red[tid][2] + red[tid][3];
}

// ---------------- selective scan: dt inline, depth-4 reg prefetch, fused epilogue --------
// grid = 512 blocks (4 b x 128 chunks of 32 channels), 256 threads = 4 waves.
// lane = ch(0..7) + 8*g(0..7); each lane owns 2 states of channel e.
struct ScanIn { float x[4], z[4], d0[4], d1[4], B0[4], B1[4], C0[4], C1[4]; };

__device__ __forceinline__ void scan_load(
    ScanIn& s, const float* xap, const float* zp, const float* dp, int t0, int g)
{
  #pragma unroll
  for (int u = 0; u < 4; ++u) {
    const int t = t0 + u;
    s.x[u] = xap[(size_t)t * EDIM];
    s.z[u] = zp[(size_t)t * 8192];
    const float* dr = dp + (size_t)t * 34;
    s.d0[u] = dr[0];           s.d1[u] = dr[1];
    s.B0[u] = dr[2 + 2 * g];   s.B1[u] = dr[3 + 2 * g];
    s.C0[u] = dr[18 + 2 * g];  s.C1[u] = dr[19 + 2 * g];
  }
}

__device__ __forceinline__ void scan_step(
    const ScanIn& s, float& h0, float& h1,
    float w0, float w1, float bde, float Aa0, float Aa1, float dpe,
    int g, unsigned short* yp, int t0)
{
  #pragma unroll
  for (int u = 0; u < 4; ++u) {
    float v = fmaf(s.d1[u], w1, fmaf(s.d0[u], w0, bde));
    float dta = (v > 20.f) ? v : log1pf(__expf(v));
    float dtxa = dta * s.x[u];
    h0 = fmaf(__expf(dta * Aa0), h0, dtxa * s.B0[u]);
    h1 = fmaf(__expf(dta * Aa1), h1, dtxa * s.B1[u]);
    float part = fmaf(h0, s.C0[u], h1 * s.C1[u]);
    part += __shfl_xor(part, 8);
    part += __shfl_xor(part, 16);
    part += __shfl_xor(part, 32);
    if (g == 0) {
      float yv = fmaf(dpe, s.x[u], part);
      yp[(size_t)(t0 + u) * EDIM] = f2bf(yv * silu_f(s.z[u]));
    }
  }
}

__global__ __launch_bounds__(256) void scan_kernel(
    const float* __restrict__ xz, const float* __restrict__ xa,
    const float* __restrict__ dbc,
    const float* __restrict__ Wdt, const float* __restrict__ bdt,
    const float* __restrict__ Alog, const float* __restrict__ Dpp,
    unsigned short* __restrict__ ybf)
{
  const int b = blockIdx.x >> 7;
  const int chunk = blockIdx.x & 127;
  const int wave = threadIdx.x >> 6;
  const int lane = threadIdx.x & 63;
  const int ch = lane & 7;
  const int g = lane >> 3;
  const int e = chunk * 32 + wave * 8 + ch;

  const float w0 = Wdt[e], w1 = Wdt[EDIM + e], bde = bdt[e];
  const float Aa0 = -expf(Alog[(size_t)e * 16 + g * 2]);
  const float Aa1 = -expf(Alog[(size_t)e * 16 + g * 2 + 1]);
  const float dpe = Dpp[e];
  float h0 = 0.f, h1 = 0.f;

  const float* xap = xa + (size_t)(b << 8) * EDIM + e;
  const float* zp  = xz + (size_t)(b << 8) * 8192 + EDIM + e;
  const float* dp  = dbc + (size_t)(b << 8) * 34;
  unsigned short* yp = ybf + (size_t)(b << 8) * EDIM + e;

  ScanIn sa, sb;
  scan_load(sa, xap, zp, dp, 0, g);
  for (int t0 = 0; t0 < LSEQ; t0 += 8) {
    scan_load(sb, xap, zp, dp, t0 + 4, g);
    scan_step(sa, h0, h1, w0, w1, bde, Aa0, Aa1, dpe, g, yp, t0);
    if (t0 + 8 < LSEQ) scan_load(sa, xap, zp, dp, t0 + 8, g);
    scan_step(sb, h0, h1, w0, w1, bde, Aa0, Aa1, dpe, g, yp, t0 + 4);
  }
}

// ---------------- small head GEMMs ----------------
__global__ __launch_bounds__(256) void head_gemm_kernel(
    const float* __restrict__ in, int row_stride,
    const float* __restrict__ W, const float* __restrict__ bias,
    float* __restrict__ outp, int K, int N, int act)
{
  __shared__ float sIn[2048];
  const float* inr = in + (size_t)blockIdx.y * row_stride;
  for (int k = threadIdx.x; k < K; k += 256) sIn[k] = inr[k];
  __syncthreads();
  int j = blockIdx.x * 256 + threadIdx.x;
  float acc = bias[j];
  #pragma unroll 4
  for (int k = 0; k < K; ++k)
    acc = fmaf(sIn[k], W[(size_t)k * N + j], acc);
  if (act == 1) acc = silu_f(acc);
  else if (act == 2) acc = (acc > 0.f) ? acc : 0.01f * acc;
  outp[(size_t)blockIdx.y * N + j] = acc;
}

__global__ __launch_bounds__(256) void head_final_kernel(
    const float* __restrict__ g2, const float* __restrict__ W,
    const float* __restrict__ bb, float* __restrict__ out)
{
  int b_idx = threadIdx.x >> 6;   // 0..3
  int lane = threadIdx.x & 63;
  float s = 0.f;
  #pragma unroll
  for (int i = 0; i < 4; ++i) {
    int k = lane + i * 64;
    s = fmaf(g2[b_idx * 256 + k], W[k], s);
  }
  #pragma unroll
  for (int o = 32; o > 0; o >>= 1) s += __shfl_down(s, o);
  if (lane == 0) out[b_idx] = 1.f / (1.f + __expf(-(s + bb[0])));
}

extern "C" void kernel_launch(void* const* d_in, const int* in_sizes, int n_in,
                              void* d_out, int out_size, void* d_ws, size_t ws_size,
                              hipStream_t stream)
{
  const float* x      = (const float*)d_in[0];
  const float* W_emb  = (const float*)d_in[1];
  const float* b_emb  = (const float*)d_in[2];
  const float* norm_w = (const float*)d_in[3];
  const float* W_in   = (const float*)d_in[4];
  const float* b_in   = (const float*)d_in[5];
  const float* conv_w = (const float*)d_in[6];
  const float* conv_b = (const float*)d_in[7];
  const float* W_x    = (const float*)d_in[8];
  const float* W_dt   = (const float*)d_in[9];
  const float* b_dt   = (const float*)d_in[10];
  const float* A_log  = (const float*)d_in[11];
  const float* Dp     = (const float*)d_in[12];
  const float* W_out  = (const float*)d_in[13];
  const float* b_out  = (const float*)d_in[14];
  const float* W_f    = (const float*)d_in[15];
  const float* b_f    = (const float*)d_in[16];
  const float* W_h1   = (const float*)d_in[17];
  const float* b_h1   = (const float*)d_in[18];
  const float* W_h2   = (const float*)d_in[19];
  const float* b_h2   = (const float*)d_in[20];
  const float* W_h3   = (const float*)d_in[21];
  const float* b_h3   = (const float*)d_in[22];
  float* out = (float*)d_out;

  // workspace layout
  char* ws = (char*)d_ws;
  float*          h   = (float*)ws;                 ws += (size_t)1024 * 2048 * 4;  //  8 MB
  unsigned short* ubf = (unsigned short*)ws;        ws += (size_t)1024 * 2048 * 2;  //  4 MB
  float*          xz  = (float*)ws;                 ws += (size_t)1024 * 8192 * 4;  // 32 MB
  float*          xa  = (float*)ws;                 ws += (size_t)1024 * 4096 * 4;  // 16 MB
  float*          dbc = (float*)ws;                 ws += (size_t)1024 * 40 * 4;
  unsigned short* ybf = (unsigned short*)ws;        ws += (size_t)1024 * 4096 * 2;  //  8 MB
  unsigned short* WT  = (unsigned short*)ws;        ws += (size_t)8192 * 2048 * 2;  // 33.6 MB
  float*          fb  = (float*)ws;                 ws += 4096 * 4;
  float*          g1b = (float*)ws;                 ws += 2048 * 4;
  float*          g2b = (float*)ws;                 ws += 1024 * 4;

  embed_kernel<<<dim3(D_MODEL / 256, 1024), 256, 0, stream>>>(x, W_emb, b_emb, h);

  for (int i = 0; i < NLAYER; ++i) {
    const float* Wi  = W_in  + (size_t)i * 2048 * 8192;
    const float* bi  = b_in  + (size_t)i * 8192;
    const float* cwi = conv_w + (size_t)i * 4096 * 4;
    const float* cbi = conv_b + (size_t)i * 4096;
    const float* Wxi = W_x   + (size_t)i * 4096 * 34;
    const float* Wdti= W_dt  + (size_t)i * 2 * 4096;
    const float* bdti= b_dt  + (size_t)i * 4096;
    const float* Ali = A_log + (size_t)i * 4096 * 16;
    const float* Dpi = Dp    + (size_t)i * 4096;
    const float* Woi = W_out + (size_t)i * 4096 * 2048;
    const float* boi = b_out + (size_t)i * 2048;
    const float* nwi = norm_w + (size_t)i * 2048;

    rmsnorm_kernel<<<1024, 256, 0, stream>>>(h, nwi, ubf);
    // WT = W_in^T (8192 x 2048 bf16)
    wtrans_kernel<<<dim3(8192 / 64, 2048 / 64), 256, 0, stream>>>(Wi, WT, 2048, 8192);
    // xz = ubf @ WT^T + b_in   (M=1024, N=8192, K=2048)
    gemm_bf16<128><<<dim3(8192 / 128, 1024 / 128), 256, 0, stream>>>(
        ubf, 2048, WT, 2048, bi, nullptr, 0, xz, 8192, 2048);
    conv_dbc_kernel<<<1024, 256, 0, stream>>>(xz, cwi, cbi, Wxi, xa, dbc);
    scan_kernel<<<512, 256, 0, stream>>>(xz, xa, dbc, Wdti, bdti, Ali, Dpi, ybf);
    // WT = W_out^T (2048 x 4096 bf16)
    wtrans_kernel<<<dim3(2048 / 64, 4096 / 64), 256, 0, stream>>>(Woi, WT, 4096, 2048);
    // h = h + ybf @ WT^T + b_out   (M=1024, N=2048, K=4096), 256 blocks
    gemm_bf16<64><<<dim3(2048 / 64, 1024 / 128), 256, 0, stream>>>(
        ybf, 4096, WT, 4096, boi, h, 2048, h, 2048, 4096);
  }

  head_gemm_kernel<<<dim3(1024 / 256, BATCH), 256, 0, stream>>>(
      h + (size_t)255 * 2048, 256 * 2048, W_f, b_f, fb, 2048, 1024, 0);
  head_gemm_kernel<<<dim3(512 / 256, BATCH), 256, 0, stream>>>(
      fb, 1024, W_h1, b_h1, g1b, 1024, 512, 1);
  head_gemm_kernel<<<dim3(256 / 256, BATCH), 256, 0, stream>>>(
      g1b, 512, W_h2, b_h2, g2b, 512, 256, 2);
  head_final_kernel<<<1, 256, 0, stream>>>(g2b, W_h3, b_h3, out);
}